// Round 6
// baseline (113.961 us; speedup 1.0000x reference)
//
#include <hip/hip_runtime.h>
#include <hip/hip_bf16.h>

// out[b] = 0.1*log1p(1/S_b),  S_b = sum_k exp2(z*H(z) + log2(w_k)), z=(1-ip)/2
// R9: raise TLP. R3..R8 proved duration (~45us) invariant to VALU load,
// LDS volume, barriers, staging -> latency-bound at 8-16 waves/CU (25-50%).
// Row-parallel decomposition caps waves at 4096 (16 rows/wave minimum for
// 16x16 MFMA). New axis: split the COLUMN loop across 2 waves sharing the
// same 16 rows (wave wv sums cgs wv*8..wv*8+8), partials combined via 128B
// LDS at the end. 4096 blocks x 128 thr -> 8192 waves, 24-32 waves/CU.
// No B prefetch ping-pong (TLP hides latency now); VGPR kept low for
// occupancy via __launch_bounds__(128, 6). Math identical; only the fp
// accumulation order of the all-positive column sum changes.

typedef __attribute__((ext_vector_type(8))) short short8;   // 8 bf16
typedef __attribute__((ext_vector_type(4))) float f32x4;
typedef __attribute__((ext_vector_type(2))) float f32x2;

#define KP 1024
#define DD 128

__device__ __forceinline__ unsigned int f2bf(float f) {
  unsigned int u = __float_as_uint(f);
  return (u + 0x7FFFu + ((u >> 16) & 1u)) >> 16;   // RNE fp32->bf16
}

// packed dual-fp32 via vector IR (backend selects v_pk_* with correct mods)
__device__ __forceinline__ f32x2 pk_fma(f32x2 a, f32x2 b, f32x2 c) {
  return __builtin_elementwise_fma(a, b, c);
}

// ---- prep: unchanged (verified R6/R7/R8). Col norms -> inv, lw=log2(w),
// bf16 normalized prototypes staged: unit(16B) = cg*1024 + w0*64 + c.
__global__ __launch_bounds__(256) void prep_kernel(
    const float* __restrict__ mus, const float* __restrict__ alphas,
    uint4* __restrict__ musbf_sw, float* __restrict__ lw) {
  __shared__ float psum[8][32];
  __shared__ float Tt[32][129];
  __shared__ float inv_s[32];
  const int t = threadIdx.x;
  const int k0 = blockIdx.x * 32;
  const int kk = t & 31, gg = t >> 5;
  float s = 0.0f;
  for (int i = 0; i < 16; ++i) {
    float v = mus[(gg * 16 + i) * KP + k0 + kk];
    s = fmaf(v, v, s);
  }
  psum[gg][kk] = s;
  __syncthreads();
  if (t < 32) {
    float tot = 0.0f;
    for (int j = 0; j < 8; ++j) tot += psum[j][t];
    inv_s[t] = rsqrtf(tot);
    lw[k0 + t] = -14.4269504089f * alphas[k0 + t];   // log2(exp(-10a))
  }
  for (int i = 0; i < 16; ++i) {            // transpose 128x32 tile via LDS
    int e = i * 256 + t;
    Tt[e & 31][e >> 5] = mus[(e >> 5) * KP + k0 + (e & 31)];
  }
  __syncthreads();
  #pragma unroll
  for (int i = 0; i < 2; ++i) {             // 512 units, coalesced 16B writes
    int u = i * 256 + t;
    int w0 = u >> 5, c32 = u & 31;
    int col = k0 + c32;
    float inv = inv_s[c32];
    uint4 o;
    o.x = f2bf(Tt[c32][w0 * 8 + 0] * inv) | (f2bf(Tt[c32][w0 * 8 + 1] * inv) << 16);
    o.y = f2bf(Tt[c32][w0 * 8 + 2] * inv) | (f2bf(Tt[c32][w0 * 8 + 3] * inv) << 16);
    o.z = f2bf(Tt[c32][w0 * 8 + 4] * inv) | (f2bf(Tt[c32][w0 * 8 + 5] * inv) << 16);
    o.w = f2bf(Tt[c32][w0 * 8 + 6] * inv) | (f2bf(Tt[c32][w0 * 8 + 7] * inv) << 16);
    musbf_sw[((col >> 6) << 10) + (w0 << 6) + (col & 63)] = o;
  }
}

// ---- main: 4096 blocks x 128 thr (2 waves). Block owns rows b*16..+16;
// BOTH waves load the same A frags; wave wv sums col-groups wv*8..wv*8+8.
// B frags loaded straight from global per kkk-chunk (4 short8 loads -> 4
// MFMAs); L1/L2 serve the shared 16KiB/cg tiles. Partial sums combined
// through a 128B LDS buffer at the end (single barrier in the kernel).
__global__ __launch_bounds__(128, 6) void main_kernel(
    const float* __restrict__ xs, const uint4* __restrict__ musbf_sw,
    const float* __restrict__ lw, float* __restrict__ out) {
  __shared__ float part[2][16];
  const int t = threadIdx.x;                 // 0..127
  const int wv = t >> 6, ln = t & 63, q = ln >> 4, l15 = ln & 15;

  // A frags: afr[kkk] = xs[row][kkk*32 + q*8 .. +8], row = block*16 + l15
  const int row = blockIdx.x * 16 + l15;
  const float4* xs4 = (const float4*)xs;
  const int base4 = row * 32 + q * 2;
  short8 afr[4];
  #pragma unroll
  for (int kkk = 0; kkk < 4; ++kkk) {
    float4 f0 = xs4[base4 + kkk * 8];
    float4 f1 = xs4[base4 + kkk * 8 + 1];
    union { short8 s; uint4 u; } a;
    a.u.x = f2bf(f0.x) | (f2bf(f0.y) << 16);
    a.u.y = f2bf(f0.z) | (f2bf(f0.w) << 16);
    a.u.z = f2bf(f1.x) | (f2bf(f1.y) << 16);
    a.u.w = f2bf(f1.z) | (f2bf(f1.w) << 16);
    afr[kkk] = a.s;
  }

  // packed constants (register pairs, loop-invariant)
  const f32x2 C_mh = {-0.5f, -0.5f}, C_ph = {0.5f, 0.5f};
  const f32x2 C_z0 = {0.0f, 0.0f};
  const f32x2 C5 = {-3.6067376f, -3.6067376f};
  const f32x2 C4 = {-2.3449500f, -2.3449500f};
  const f32x2 C3 = {-3.2975886f, -3.2975886f};
  const f32x2 C2 = {-5.1295823f, -5.1295823f};
  const f32x2 C1 = {-9.6179669f, -9.6179669f};
  const f32x2 C0 = {-28.8539008f, -28.8539008f};

  f32x2 sums2[2] = {(f32x2){0.f, 0.f}, (f32x2){0.f, 0.f}};   // rows (0,1),(2,3)

  const short8* __restrict__ B8 = (const short8*)musbf_sw;
  const int ub = q * 64 + l15;              // lane's unit offset within tile

  for (int cgi = 0; cgi < 8; ++cgi) {
    const int cg = wv * 8 + cgi;
    float lwv[4];
    #pragma unroll
    for (int nt = 0; nt < 4; ++nt) lwv[nt] = lw[cg * 64 + nt * 16 + l15];

    f32x4 acc[4];
    #pragma unroll
    for (int nt = 0; nt < 4; ++nt) acc[nt] = (f32x4){0.f, 0.f, 0.f, 0.f};

    // per kkk-chunk: 4 independent short8 loads feed 4 MFMAs
    #pragma unroll
    for (int kkk = 0; kkk < 4; ++kkk) {
      short8 b0 = B8[cg * 1024 + kkk * 256 + ub];
      short8 b1 = B8[cg * 1024 + kkk * 256 + ub + 16];
      short8 b2 = B8[cg * 1024 + kkk * 256 + ub + 32];
      short8 b3 = B8[cg * 1024 + kkk * 256 + ub + 48];
      acc[0] = __builtin_amdgcn_mfma_f32_16x16x32_bf16(afr[kkk], b0, acc[0], 0, 0, 0);
      acc[1] = __builtin_amdgcn_mfma_f32_16x16x32_bf16(afr[kkk], b1, acc[1], 0, 0, 0);
      acc[2] = __builtin_amdgcn_mfma_f32_16x16x32_bf16(afr[kkk], b2, acc[2], 0, 0, 0);
      acc[3] = __builtin_amdgcn_mfma_f32_16x16x32_bf16(afr[kkk], b3, acc[3], 0, 0, 0);
    }

    // packed epilogue: term = exp2(z*H(z) + lw), z=(1-x)/2
    #pragma unroll
    for (int nt = 0; nt < 4; ++nt) {
      f32x2 lwp = {lwv[nt], lwv[nt]};
      #pragma unroll
      for (int p = 0; p < 2; ++p) {
        f32x2 x = {acc[nt][2 * p], acc[nt][2 * p + 1]};
        f32x2 z = pk_fma(x, C_mh, C_ph);
        z = __builtin_elementwise_max(z, C_z0);
        f32x2 h = pk_fma(z, C5, C4);
        h = pk_fma(z, h, C3);
        h = pk_fma(z, h, C2);
        h = pk_fma(z, h, C1);
        h = pk_fma(z, h, C0);
        f32x2 arg = pk_fma(z, h, lwp);
        f32x2 e = {__builtin_amdgcn_exp2f(arg.x), __builtin_amdgcn_exp2f(arg.y)};
        sums2[p] = sums2[p] + e;
      }
    }
  }

  // reduce over the 16 col-lanes (xor 1,2,4,8 stays within l15 group)
  float s[4] = {sums2[0].x, sums2[0].y, sums2[1].x, sums2[1].y};
  #pragma unroll
  for (int s2 = 1; s2 < 16; s2 <<= 1)
    #pragma unroll
    for (int r = 0; r < 4; ++r) s[r] += __shfl_xor(s[r], s2, 64);

  // combine the two waves' col-half partials through LDS
  if (l15 == 0) {
    #pragma unroll
    for (int r = 0; r < 4; ++r) part[wv][q * 4 + r] = s[r];
  }
  __syncthreads();
  if (t < 16) {
    float S = part[0][t] + part[1][t];
    out[blockIdx.x * 16 + t] = 0.1f * log1pf(1.0f / S);
  }
}

extern "C" void kernel_launch(void* const* d_in, const int* in_sizes, int n_in,
                              void* d_out, int out_size, void* d_ws, size_t ws_size,
                              hipStream_t stream) {
  const float* xs     = (const float*)d_in[0];   // [65536,128]
  const float* mus    = (const float*)d_in[1];   // [128,1024]
  const float* alphas = (const float*)d_in[2];   // [1024]
  float* out = (float*)d_out;

  uint4* musbf_sw = (uint4*)d_ws;                              // 256 KiB
  float* lw = (float*)((char*)d_ws + 16384 * sizeof(uint4));   // 4 KiB

  prep_kernel<<<KP / 32, 256, 0, stream>>>(mus, alphas, musbf_sw, lw);
  const int B = in_sizes[0] / DD;   // 65536
  main_kernel<<<B / 16, 128, 0, stream>>>(xs, musbf_sw, lw, out);
}